// Round 1
// baseline (2026.213 us; speedup 1.0000x reference)
//
#include <hip/hip_runtime.h>

#define DN  256   // DAGs
#define NN  1024  // nodes per DAG
#define PP  8     // max predecessors
#define LL  104   // feature dim
#define CLS 500   // classes

// One block per DAG. Sequential over nodes (true data dependency), parallel
// over features within a node. Outputs live in d_ws ([DN][NN][LL] f32).
__global__ __launch_bounds__(256) void dag_seq_kernel(
    const float* __restrict__ atom,      // [DN][NN][LL]
    const int*   __restrict__ pred,      // [DN][NN][PP]
    const float* __restrict__ W_single,  // [LL][LL]
    const float* __restrict__ b_single,  // [LL]
    const float* __restrict__ W_merge,   // [LL][2*LL]
    const float* __restrict__ b_merge,   // [LL]
    const float* __restrict__ attn_w,    // [LL]
    float* __restrict__ out_all,         // ws: [DN][NN][LL]
    float* __restrict__ last_buf)        // ws: [DN][LL]
{
    // Transposed merge weights: sWmT[l][r] = W_merge[r][l].
    // Matvec reads sWmT[l][r] with lanes consecutive in r -> conflict-free.
    __shared__ float sWmT[2*LL][LL];
    __shared__ float s_x[2*LL];          // concat(agg, feat)
    __shared__ float s_bm[LL];
    __shared__ float s_attn[LL];

    const int d   = blockIdx.x;
    const int tid = threadIdx.x;

    for (int idx = tid; idx < LL*2*LL; idx += 256) {
        int r = idx / (2*LL);
        int l = idx - r*(2*LL);
        sWmT[l][r] = W_merge[idx];
    }
    if (tid < LL) { s_attn[tid] = attn_w[tid]; s_bm[tid] = b_merge[tid]; }
    __syncthreads();

    const float* atom_d = atom + (size_t)d * NN * LL;
    const int*   pred_d = pred + (size_t)d * NN * PP;
    float*       out_d  = out_all + (size_t)d * NN * LL;

    // ---- node 0: root path (no predecessors) ----
    if (tid < LL) s_x[tid] = atom_d[tid];
    __syncthreads();
    if (tid < LL) {
        float acc = b_single[tid];
        const float* wr = W_single + tid*LL;
        #pragma unroll 8
        for (int l = 0; l < LL; ++l) acc = fmaf(wr[l], s_x[l], acc);
        out_d[tid] = fmaxf(acc, 0.f);
    }
    __syncthreads();

    // prefetch pred indices (uniform -> SGPR) and feat for n=1
    int pi_nxt[PP];
    #pragma unroll
    for (int p = 0; p < PP; ++p) pi_nxt[p] = pred_d[1*PP + p];
    float feat_next = 0.f;
    if (tid < LL) feat_next = atom_d[1*LL + tid];

    for (int n = 1; n < NN; ++n) {
        int pi[PP];
        #pragma unroll
        for (int p = 0; p < PP; ++p) pi[p] = pi_nxt[p];
        float feat = feat_next;

        // prefetch next node's indices + features (hides HBM latency)
        if (n + 1 < NN) {
            #pragma unroll
            for (int p = 0; p < PP; ++p) pi_nxt[p] = pred_d[(n+1)*PP + p];
            if (tid < LL) feat_next = atom_d[(n+1)*LL + tid];
        }

        // ---- phase 1: gather predecessor outputs + per-feature softmax ----
        if (tid < LL) {
            float po[PP];
            #pragma unroll
            for (int p = 0; p < PP; ++p)
                po[p] = (pi[p] >= 0) ? out_d[pi[p]*LL + tid] : 0.f;

            float aw = s_attn[tid];
            float m = -1e30f;
            #pragma unroll
            for (int p = 0; p < PP; ++p)
                if (pi[p] >= 0) m = fmaxf(m, aw * po[p]);
            float den = 0.f, num = 0.f;
            #pragma unroll
            for (int p = 0; p < PP; ++p) {
                if (pi[p] >= 0) {
                    float e = __expf(aw * po[p] - m);
                    den += e;
                    num = fmaf(e, po[p], num);
                }
            }
            s_x[tid]      = num / den;  // agg  (>=1 valid pred for n>=1)
            s_x[LL + tid] = feat;
        }
        __syncthreads();

        // ---- phase 2: merged = relu(W_merge @ [agg, feat] + b), 2 thr/row ----
        {
            const int r = tid >> 1;
            const int h = tid & 1;
            if (r < LL) {
                float acc = 0.f;
                const int base = h * LL;
                #pragma unroll 8
                for (int l = 0; l < LL; ++l)
                    acc = fmaf(sWmT[base + l][r], s_x[base + l], acc);
                acc += __shfl_xor(acc, 1);
                if (h == 0) {
                    float v = fmaxf(acc + s_bm[r], 0.f);
                    out_d[n*LL + r] = v;
                    if (n == NN - 1) last_buf[d*LL + r] = v;
                }
            }
        }
        __syncthreads();  // make stores visible before next node's gather
    }
}

// Cross-DAG softmax pool + final classifier. Single block.
__global__ __launch_bounds__(256) void final_pool_kernel(
    const float* __restrict__ last_buf,  // [DN][LL]
    const float* __restrict__ dag_w,     // [LL]
    const float* __restrict__ W_final,   // [CLS][LL]
    const float* __restrict__ b_final,   // [CLS]
    float* __restrict__ out)             // [CLS]
{
    __shared__ float s_pooled[LL];
    const int tid = threadIdx.x;

    if (tid < LL) {
        float dw = dag_w[tid];
        float m = -1e30f;
        #pragma unroll 8
        for (int d = 0; d < DN; ++d)
            m = fmaxf(m, dw * last_buf[d*LL + tid]);
        float den = 0.f, num = 0.f;
        #pragma unroll 8
        for (int d = 0; d < DN; ++d) {
            float v = last_buf[d*LL + tid];
            float e = __expf(dw * v - m);
            den += e;
            num = fmaf(e, v, num);
        }
        s_pooled[tid] = num / den;
    }
    __syncthreads();

    for (int c = tid; c < CLS; c += 256) {
        float acc = b_final[c];
        const float* wr = W_final + c*LL;
        #pragma unroll 8
        for (int l = 0; l < LL; ++l) acc = fmaf(wr[l], s_pooled[l], acc);
        out[c] = acc;
    }
}

extern "C" void kernel_launch(void* const* d_in, const int* in_sizes, int n_in,
                              void* d_out, int out_size, void* d_ws, size_t ws_size,
                              hipStream_t stream) {
    const float* atom     = (const float*)d_in[0];
    const int*   pred     = (const int*)  d_in[1];
    const float* W_single = (const float*)d_in[2];
    const float* b_single = (const float*)d_in[3];
    const float* W_merge  = (const float*)d_in[4];
    const float* b_merge  = (const float*)d_in[5];
    const float* attn_w   = (const float*)d_in[6];
    const float* dag_w    = (const float*)d_in[7];
    const float* W_final  = (const float*)d_in[8];
    const float* b_final  = (const float*)d_in[9];
    float* out = (float*)d_out;

    float* out_all  = (float*)d_ws;                       // [DN][NN][LL]
    float* last_buf = out_all + (size_t)DN * NN * LL;     // [DN][LL]

    dag_seq_kernel<<<DN, 256, 0, stream>>>(atom, pred, W_single, b_single,
                                           W_merge, b_merge, attn_w,
                                           out_all, last_buf);
    final_pool_kernel<<<1, 256, 0, stream>>>(last_buf, dag_w, W_final, b_final, out);
}

// Round 2
// 808.286 us; speedup vs baseline: 2.5068x; 2.5068x over previous
//
#include <hip/hip_runtime.h>

#define DN  256   // DAGs
#define NN  1024  // nodes per DAG
#define PP  8     // max predecessors
#define LL  104   // feature dim
#define CLS 500   // classes
#define BT  512   // threads per block
#define TMAX 32   // node tile per level pass

// One block per DAG. Level-scheduled: relax levels in LDS, counting-sort,
// then process levels in parallel tiles (gather+softmax -> blocked matvec).
__global__ __launch_bounds__(BT) void dag_level_kernel(
    const float* __restrict__ atom,      // [DN][NN][LL]
    const int*   __restrict__ pred,      // [DN][NN][PP]
    const float* __restrict__ W_single,  // [LL][LL]
    const float* __restrict__ b_single,  // [LL]
    const float* __restrict__ W_merge,   // [LL][2*LL]
    const float* __restrict__ b_merge,   // [LL]
    const float* __restrict__ attn_w,    // [LL]
    float* __restrict__ out_all,         // ws: [DN][NN][LL]
    float* __restrict__ last_buf)        // ws: [DN][LL]
{
    __shared__ float sW[2*LL][LL];          // 86.5 KB: sW[c][r] = W[r][c] (transposed)
    __shared__ float x_buf[TMAX][2*LL];     // 26.6 KB: [agg | feat] per tile node
    __shared__ float partial[2][TMAX][LL];  // 26.6 KB: K-split partial sums
    __shared__ int   lvl[NN];               // 4 KB
    __shared__ int   cnt[NN];               // 4 KB: histogram -> offsets
    __shared__ unsigned short order[NN];    // 2 KB
    __shared__ float s_attn[LL], s_bm[LL];
    __shared__ int   csum[64];
    __shared__ int   s_flag, s_maxlvl;

    const int d   = blockIdx.x;
    const int tid = threadIdx.x;

    const float* atom_d = atom + (size_t)d * NN * LL;
    const int*   pred_d = pred + (size_t)d * NN * PP;
    float*       out_d  = out_all + (size_t)d * NN * LL;

    if (tid < LL) { s_attn[tid] = attn_w[tid]; s_bm[tid] = b_merge[tid]; }
    if (tid == 0) s_maxlvl = 0;
    for (int n = tid; n < NN; n += BT) lvl[n] = 0;
    __syncthreads();

    // ---- 1. level relaxation: lvl[n] = 1 + max(lvl[valid preds]) ----
    for (int it = 0; it < NN; ++it) {
        __syncthreads();
        if (tid == 0) s_flag = 0;
        __syncthreads();
        bool ch = false;
        #pragma unroll
        for (int k = 0; k < NN / BT; ++k) {
            int n = tid + k * BT;
            int mx = -1;
            #pragma unroll
            for (int p = 0; p < PP; ++p) {
                int pi = pred_d[n * PP + p];
                if (pi >= 0) mx = max(mx, lvl[pi]);
            }
            int nl = mx + 1;   // no valid preds -> level 0
            if (nl != lvl[n]) { lvl[n] = nl; ch = true; }
        }
        if (ch) s_flag = 1;
        __syncthreads();
        if (s_flag == 0) break;
    }
    {   // max level
        int mymax = 0;
        for (int n = tid; n < NN; n += BT) mymax = max(mymax, lvl[n]);
        atomicMax(&s_maxlvl, mymax);
    }

    // ---- 2. counting sort by level ----
    for (int i = tid; i < NN; i += BT) cnt[i] = 0;
    __syncthreads();
    for (int n = tid; n < NN; n += BT) atomicAdd(&cnt[lvl[n]], 1);
    __syncthreads();
    if (tid < 64) { int s = 0; for (int i = 0; i < 16; ++i) s += cnt[tid*16 + i]; csum[tid] = s; }
    __syncthreads();
    if (tid == 0) { int run = 0; for (int t = 0; t < 64; ++t) { int c = csum[t]; csum[t] = run; run += c; } }
    __syncthreads();
    if (tid < 64) {
        int run = csum[tid];
        for (int i = 0; i < 16; ++i) { int c = cnt[tid*16 + i]; cnt[tid*16 + i] = run; run += c; }
    }
    __syncthreads();
    for (int n = tid; n < NN; n += BT) {
        int pos = atomicAdd(&cnt[lvl[n]], 1);
        order[pos] = (unsigned short)n;
    }
    __syncthreads();
    // post-scatter: level L occupies [L==0 ? 0 : cnt[L-1], cnt[L])

    // ---- 3. level-0 (root-path) nodes via W_single ----
    for (int idx = tid; idx < LL * LL; idx += BT) {
        int r = idx / LL, l = idx - r * LL;
        sW[l][r] = W_single[idx];
    }
    __syncthreads();
    {
        int nroots = cnt[0];
        for (int task = tid; task < nroots * LL; task += BT) {
            int ni = task / LL, r = task - ni * LL;
            int n = order[ni];
            float acc = b_single[r];
            #pragma unroll 8
            for (int l = 0; l < LL; ++l)
                acc = fmaf(sW[l][r], atom_d[n * LL + l], acc);
            float v = fmaxf(acc, 0.f);
            out_d[n * LL + r] = v;
            if (n == NN - 1) last_buf[d * LL + r] = v;
        }
    }
    __syncthreads();

    // ---- 4. stage W_merge transposed ----
    for (int idx = tid; idx < LL * 2 * LL; idx += BT) {
        int r = idx / (2 * LL), c = idx - r * (2 * LL);
        sW[c][r] = W_merge[idx];
    }
    __syncthreads();

    // ---- 5. main level loop ----
    const int maxlvl = s_maxlvl;
    for (int L = 1; L <= maxlvl; ++L) {
        const int s = cnt[L - 1], e = cnt[L];
        for (int t0 = s; t0 < e; t0 += TMAX) {
            const int tc = min(TMAX, e - t0);

            // phase A: gather pred outputs, per-feature softmax, stage feat
            for (int task = tid; task < tc * LL; task += BT) {
                int ni = task / LL, l = task - ni * LL;
                int n = order[t0 + ni];
                const int* pp = pred_d + n * PP;
                float aw = s_attn[l];
                int pi[PP];
                #pragma unroll
                for (int p = 0; p < PP; ++p) pi[p] = pp[p];
                float po[PP];
                float m = -1e30f;
                #pragma unroll
                for (int p = 0; p < PP; ++p) {
                    po[p] = (pi[p] >= 0) ? out_d[pi[p] * LL + l] : 0.f;
                    if (pi[p] >= 0) m = fmaxf(m, aw * po[p]);
                }
                float den = 0.f, num = 0.f;
                #pragma unroll
                for (int p = 0; p < PP; ++p) {
                    if (pi[p] >= 0) {
                        float ex = __expf(fmaf(aw, po[p], -m));
                        den += ex;
                        num = fmaf(ex, po[p], num);
                    }
                }
                x_buf[ni][l]      = num / den;
                x_buf[ni][LL + l] = atom_d[n * LL + l];
            }
            __syncthreads();

            // phase B: out[r] += sum_c sW[c][r]*x[c], 2-row x 4-node x K-split-2
            const int ngc = (tc + 3) >> 2;
            const int ntask = 52 * ngc * 2;
            for (int task = tid; task < ntask; task += BT) {
                int rb = task % 52;
                int t2 = task / 52;
                int kc = t2 & 1;
                int ng = t2 >> 1;
                const int koff = kc * LL;
                const int r0 = rb * 2;
                const int n0 = ng * 4;
                float a0x = 0.f, a0y = 0.f, a1x = 0.f, a1y = 0.f;
                float a2x = 0.f, a2y = 0.f, a3x = 0.f, a3y = 0.f;
                #pragma unroll 4
                for (int l = 0; l < LL; ++l) {
                    float2 w = *(const float2*)&sW[koff + l][r0];
                    float x0 = x_buf[n0 + 0][koff + l];
                    float x1 = x_buf[n0 + 1][koff + l];
                    float x2 = x_buf[n0 + 2][koff + l];
                    float x3 = x_buf[n0 + 3][koff + l];
                    a0x = fmaf(w.x, x0, a0x); a0y = fmaf(w.y, x0, a0y);
                    a1x = fmaf(w.x, x1, a1x); a1y = fmaf(w.y, x1, a1y);
                    a2x = fmaf(w.x, x2, a2x); a2y = fmaf(w.y, x2, a2y);
                    a3x = fmaf(w.x, x3, a3x); a3y = fmaf(w.y, x3, a3y);
                }
                if (n0 + 0 < tc) *(float2*)&partial[kc][n0 + 0][r0] = make_float2(a0x, a0y);
                if (n0 + 1 < tc) *(float2*)&partial[kc][n0 + 1][r0] = make_float2(a1x, a1y);
                if (n0 + 2 < tc) *(float2*)&partial[kc][n0 + 2][r0] = make_float2(a2x, a2y);
                if (n0 + 3 < tc) *(float2*)&partial[kc][n0 + 3][r0] = make_float2(a3x, a3y);
            }
            __syncthreads();

            // phase C: reduce K-split, bias, relu, store
            for (int task = tid; task < tc * LL; task += BT) {
                int ni = task / LL, r = task - ni * LL;
                int n = order[t0 + ni];
                float v = partial[0][ni][r] + partial[1][ni][r] + s_bm[r];
                v = fmaxf(v, 0.f);
                out_d[n * LL + r] = v;
                if (n == NN - 1) last_buf[d * LL + r] = v;
            }
            __syncthreads();
        }
    }
}

// Cross-DAG softmax pool + final classifier. Single block.
__global__ __launch_bounds__(256) void final_pool_kernel(
    const float* __restrict__ last_buf,  // [DN][LL]
    const float* __restrict__ dag_w,     // [LL]
    const float* __restrict__ W_final,   // [CLS][LL]
    const float* __restrict__ b_final,   // [CLS]
    float* __restrict__ out)             // [CLS]
{
    __shared__ float s_pooled[LL];
    const int tid = threadIdx.x;

    if (tid < LL) {
        float dw = dag_w[tid];
        float m = -1e30f;
        #pragma unroll 8
        for (int dd = 0; dd < DN; ++dd)
            m = fmaxf(m, dw * last_buf[dd * LL + tid]);
        float den = 0.f, num = 0.f;
        #pragma unroll 8
        for (int dd = 0; dd < DN; ++dd) {
            float v = last_buf[dd * LL + tid];
            float e = __expf(dw * v - m);
            den += e;
            num = fmaf(e, v, num);
        }
        s_pooled[tid] = num / den;
    }
    __syncthreads();

    for (int c = tid; c < CLS; c += 256) {
        float acc = b_final[c];
        const float* wr = W_final + c * LL;
        #pragma unroll 8
        for (int l = 0; l < LL; ++l) acc = fmaf(wr[l], s_pooled[l], acc);
        out[c] = acc;
    }
}

extern "C" void kernel_launch(void* const* d_in, const int* in_sizes, int n_in,
                              void* d_out, int out_size, void* d_ws, size_t ws_size,
                              hipStream_t stream) {
    const float* atom     = (const float*)d_in[0];
    const int*   pred     = (const int*)  d_in[1];
    const float* W_single = (const float*)d_in[2];
    const float* b_single = (const float*)d_in[3];
    const float* W_merge  = (const float*)d_in[4];
    const float* b_merge  = (const float*)d_in[5];
    const float* attn_w   = (const float*)d_in[6];
    const float* dag_w    = (const float*)d_in[7];
    const float* W_final  = (const float*)d_in[8];
    const float* b_final  = (const float*)d_in[9];
    float* out = (float*)d_out;

    float* out_all  = (float*)d_ws;                       // [DN][NN][LL]
    float* last_buf = out_all + (size_t)DN * NN * LL;     // [DN][LL]

    dag_level_kernel<<<DN, BT, 0, stream>>>(atom, pred, W_single, b_single,
                                            W_merge, b_merge, attn_w,
                                            out_all, last_buf);
    final_pool_kernel<<<1, 256, 0, stream>>>(last_buf, dag_w, W_final, b_final, out);
}

// Round 3
// 419.837 us; speedup vs baseline: 4.8262x; 1.9252x over previous
//
#include <hip/hip_runtime.h>

#define DN  256   // DAGs
#define NN  1024  // nodes per DAG
#define PP  8     // max predecessors
#define LL  104   // feature dim
#define CLS 500   // classes
#define BT  1024  // threads per block (16 waves)
#define TMAX 32   // node tile per level pass
#define KP  232   // padded K stride in bf16 elems (2*LL=208 -> 232; 116 dwords ≡ 20 mod 32: conflict-free)
#define NPAD 112  // padded W rows (104 -> 112)

typedef __attribute__((ext_vector_type(8))) short short8;
typedef __attribute__((ext_vector_type(4))) float f32x4;

__device__ __forceinline__ void split_bf16(float x, unsigned short& h, unsigned short& l) {
    unsigned u = __float_as_uint(x);
    h = (unsigned short)(u >> 16);
    float hf = __uint_as_float(u & 0xFFFF0000u);
    l = (unsigned short)(__float_as_uint(x - hf) >> 16);
}

// One block per DAG. Level-scheduled; per-level matvec batch done as a
// split-bf16 MFMA GEMM: out[tc x 104] = X[tc x 208] * W^T, err ~2^-16.
__global__ __launch_bounds__(BT) void dag_level_kernel(
    const float* __restrict__ atom,      // [DN][NN][LL]
    const int*   __restrict__ pred,      // [DN][NN][PP]
    const float* __restrict__ W_single,  // [LL][LL]
    const float* __restrict__ b_single,  // [LL]
    const float* __restrict__ W_merge,   // [LL][2*LL]
    const float* __restrict__ b_merge,   // [LL]
    const float* __restrict__ attn_w,    // [LL]
    float* __restrict__ out_all,         // ws: [DN][NN][LL]
    float* __restrict__ last_buf)        // ws: [DN][LL]
{
    __shared__ __align__(16) unsigned short w_hi[NPAD][KP];  // 50.75 KB
    __shared__ __align__(16) unsigned short w_lo[NPAD][KP];  // 50.75 KB
    __shared__ __align__(16) unsigned short x_hi[TMAX][KP];  // 14.5 KB
    __shared__ __align__(16) unsigned short x_lo[TMAX][KP];  // 14.5 KB
    __shared__ int   lvl[NN];               // 4 KB
    __shared__ int   cnt[NN];               // 4 KB
    __shared__ unsigned short order[NN];    // 2 KB
    __shared__ float s_attn[LL], s_bm[LL];
    __shared__ int   csum[64];
    __shared__ int   s_flag, s_maxlvl;

    const int d   = blockIdx.x;
    const int tid = threadIdx.x;

    const float* atom_d = atom + (size_t)d * NN * LL;
    const int*   pred_d = pred + (size_t)d * NN * PP;
    float*       out_d  = out_all + (size_t)d * NN * LL;

    // ---- stage W_merge split hi/lo (pads zeroed), attn/bias, zero x pad cols ----
    for (int idx = tid; idx < NPAD * KP; idx += BT) {
        int r = idx / KP, c = idx - r * KP;
        float v = (r < LL && c < 2 * LL) ? W_merge[r * 2 * LL + c] : 0.f;
        unsigned short h, lo;
        split_bf16(v, h, lo);
        w_hi[r][c] = h; w_lo[r][c] = lo;
    }
    for (int idx = tid; idx < TMAX * (KP - 2 * LL); idx += BT) {
        int rr = idx / (KP - 2 * LL), cc = 2 * LL + (idx - rr * (KP - 2 * LL));
        x_hi[rr][cc] = 0; x_lo[rr][cc] = 0;   // NaN-safety for K pad
    }
    if (tid < LL) { s_attn[tid] = attn_w[tid]; s_bm[tid] = b_merge[tid]; }
    if (tid == 0) { s_flag = 0; s_maxlvl = 0; }

    // ---- 1. level relaxation (1 node per thread, preds in registers) ----
    int myp[PP];
    {
        const int4* pp4 = (const int4*)(pred_d + tid * PP);
        int4 a = pp4[0], b = pp4[1];
        myp[0]=a.x; myp[1]=a.y; myp[2]=a.z; myp[3]=a.w;
        myp[4]=b.x; myp[5]=b.y; myp[6]=b.z; myp[7]=b.w;
    }
    lvl[tid] = 0;
    __syncthreads();
    for (int it = 1; it <= NN; ++it) {
        int mx = -1;
        #pragma unroll
        for (int p = 0; p < PP; ++p)
            if (myp[p] >= 0) mx = max(mx, lvl[myp[p]]);
        int nl = mx + 1;
        if (nl != lvl[tid]) { lvl[tid] = nl; s_flag = it; }
        __syncthreads();
        if (s_flag != it) break;   // fixpoint: nobody changed this sweep
    }
    atomicMax(&s_maxlvl, lvl[tid]);

    // ---- 2. counting sort by level ----
    cnt[tid] = 0;
    __syncthreads();
    atomicAdd(&cnt[lvl[tid]], 1);
    __syncthreads();
    if (tid < 64) { int s = 0; for (int i = 0; i < 16; ++i) s += cnt[tid*16 + i]; csum[tid] = s; }
    __syncthreads();
    if (tid == 0) { int run = 0; for (int t = 0; t < 64; ++t) { int c = csum[t]; csum[t] = run; run += c; } }
    __syncthreads();
    if (tid < 64) {
        int run = csum[tid];
        for (int i = 0; i < 16; ++i) { int c = cnt[tid*16 + i]; cnt[tid*16 + i] = run; run += c; }
    }
    __syncthreads();
    { int pos = atomicAdd(&cnt[lvl[tid]], 1); order[pos] = (unsigned short)tid; }
    __syncthreads();
    // level L occupies [L==0 ? 0 : cnt[L-1], cnt[L])

    // ---- 3. level-0 (root) nodes via W_single straight from global ----
    {
        int nroots = cnt[0];
        for (int task = tid; task < nroots * LL; task += BT) {
            int ni = task / LL, r = task - ni * LL;
            int n = order[ni];
            float acc = b_single[r];
            const float* feat = atom_d + n * LL;
            const float* wr = W_single + r * LL;
            #pragma unroll 8
            for (int l = 0; l < LL; ++l) acc = fmaf(wr[l], feat[l], acc);
            float v = fmaxf(acc, 0.f);
            out_d[n * LL + r] = v;
            if (n == NN - 1) last_buf[d * LL + r] = v;
        }
    }
    __syncthreads();

    // ---- 4. main level loop ----
    const int maxlvl = s_maxlvl;
    const int wid  = tid >> 6;
    const int lane = tid & 63;
    for (int L = 1; L <= maxlvl; ++L) {
        const int s = cnt[L - 1], e = cnt[L];
        for (int t0 = s; t0 < e; t0 += TMAX) {
            const int tc = min(TMAX, e - t0);

            // phase A: gather pred outputs + per-feature softmax -> x (split bf16)
            for (int task = tid; task < tc * LL; task += BT) {
                int ni = task / LL, l = task - ni * LL;
                int n = order[t0 + ni];
                const int4* pp4 = (const int4*)(pred_d + n * PP);
                int4 pa = pp4[0], pb = pp4[1];
                int pi[PP] = {pa.x, pa.y, pa.z, pa.w, pb.x, pb.y, pb.z, pb.w};
                float aw = s_attn[l];
                float po[PP];
                float m = -1e30f;
                #pragma unroll
                for (int p = 0; p < PP; ++p) {
                    po[p] = (pi[p] >= 0) ? out_d[pi[p] * LL + l] : 0.f;
                    if (pi[p] >= 0) m = fmaxf(m, aw * po[p]);
                }
                float den = 0.f, num = 0.f;
                #pragma unroll
                for (int p = 0; p < PP; ++p) {
                    if (pi[p] >= 0) {
                        float ex = __expf(fmaf(aw, po[p], -m));
                        den += ex;
                        num = fmaf(ex, po[p], num);
                    }
                }
                float agg = num / den;
                float feat = atom_d[n * LL + l];
                split_bf16(agg,  x_hi[ni][l],      x_lo[ni][l]);
                split_bf16(feat, x_hi[ni][LL + l], x_lo[ni][LL + l]);
            }
            __syncthreads();

            // phase B: MFMA GEMM  C[tc x 104] = X[tc x 208(+pad)] * W^T
            {
                const int mtiles = (tc + 15) >> 4;
                const int njobs = 7 * mtiles;
                for (int job = wid; job < njobs; job += BT / 64) {
                    const int nt = job / mtiles;
                    const int mt = job - nt * mtiles;
                    const int row_a = mt * 16 + (lane & 15);
                    const int rB    = nt * 16 + (lane & 15);
                    const int kg    = (lane >> 4) * 8;
                    f32x4 acc = {0.f, 0.f, 0.f, 0.f};
                    #pragma unroll
                    for (int kt = 0; kt < 7; ++kt) {
                        const int k0 = kt * 32 + kg;
                        short8 ah = *(const short8*)&x_hi[row_a][k0];
                        short8 al = *(const short8*)&x_lo[row_a][k0];
                        short8 bh = *(const short8*)&w_hi[rB][k0];
                        short8 bl = *(const short8*)&w_lo[rB][k0];
                        acc = __builtin_amdgcn_mfma_f32_16x16x32_bf16(ah, bh, acc, 0, 0, 0);
                        acc = __builtin_amdgcn_mfma_f32_16x16x32_bf16(ah, bl, acc, 0, 0, 0);
                        acc = __builtin_amdgcn_mfma_f32_16x16x32_bf16(al, bh, acc, 0, 0, 0);
                    }
                    const int r = rB;
                    if (r < LL) {
                        #pragma unroll
                        for (int j = 0; j < 4; ++j) {
                            int ni = mt * 16 + (lane >> 4) * 4 + j;
                            if (ni < tc) {
                                int n = order[t0 + ni];
                                float v = fmaxf(acc[j] + s_bm[r], 0.f);
                                out_d[n * LL + r] = v;
                                if (n == NN - 1) last_buf[d * LL + r] = v;
                            }
                        }
                    }
                }
            }
            __syncthreads();  // x_buf reuse + out_d visibility for next tile
        }
    }
}

// Cross-DAG softmax pool + final classifier. Single block.
__global__ __launch_bounds__(256) void final_pool_kernel(
    const float* __restrict__ last_buf,  // [DN][LL]
    const float* __restrict__ dag_w,     // [LL]
    const float* __restrict__ W_final,   // [CLS][LL]
    const float* __restrict__ b_final,   // [CLS]
    float* __restrict__ out)             // [CLS]
{
    __shared__ float s_pooled[LL];
    const int tid = threadIdx.x;

    if (tid < LL) {
        float dw = dag_w[tid];
        float m = -1e30f;
        #pragma unroll 8
        for (int dd = 0; dd < DN; ++dd)
            m = fmaxf(m, dw * last_buf[dd * LL + tid]);
        float den = 0.f, num = 0.f;
        #pragma unroll 8
        for (int dd = 0; dd < DN; ++dd) {
            float v = last_buf[dd * LL + tid];
            float e = __expf(dw * v - m);
            den += e;
            num = fmaf(e, v, num);
        }
        s_pooled[tid] = num / den;
    }
    __syncthreads();

    for (int c = tid; c < CLS; c += 256) {
        float acc = b_final[c];
        const float* wr = W_final + c * LL;
        #pragma unroll 8
        for (int l = 0; l < LL; ++l) acc = fmaf(wr[l], s_pooled[l], acc);
        out[c] = acc;
    }
}

extern "C" void kernel_launch(void* const* d_in, const int* in_sizes, int n_in,
                              void* d_out, int out_size, void* d_ws, size_t ws_size,
                              hipStream_t stream) {
    const float* atom     = (const float*)d_in[0];
    const int*   pred     = (const int*)  d_in[1];
    const float* W_single = (const float*)d_in[2];
    const float* b_single = (const float*)d_in[3];
    const float* W_merge  = (const float*)d_in[4];
    const float* b_merge  = (const float*)d_in[5];
    const float* attn_w   = (const float*)d_in[6];
    const float* dag_w    = (const float*)d_in[7];
    const float* W_final  = (const float*)d_in[8];
    const float* b_final  = (const float*)d_in[9];
    float* out = (float*)d_out;

    float* out_all  = (float*)d_ws;                       // [DN][NN][LL]
    float* last_buf = out_all + (size_t)DN * NN * LL;     // [DN][LL]

    dag_level_kernel<<<DN, BT, 0, stream>>>(atom, pred, W_single, b_single,
                                            W_merge, b_merge, attn_w,
                                            out_all, last_buf);
    final_pool_kernel<<<1, 256, 0, stream>>>(last_buf, dag_w, W_final, b_final, out);
}